// Round 5
// baseline (435.089 us; speedup 1.0000x reference)
//
#include <hip/hip_runtime.h>
#include <hip/hip_bf16.h>

typedef short short8 __attribute__((ext_vector_type(8)));
typedef float f32x4 __attribute__((ext_vector_type(4)));

constexpr int BDIM = 32, RDIM = 64, CDIM = 96, NH_ = 3, HD_ = 32;
constexpr int LTOK = RDIM * RDIM;      // 4096
constexpr int GG = 64;
constexpr int HID = 384;
constexpr int NWIN = 2048;
constexpr float SCALE = 0.17677669529663687f;
constexpr long OUT1OFF = (long)BDIM * LTOK * CDIM;   // 12582912

// ws layout (bf16 element offsets): transposed weights [n][k], k-contiguous
constexpr int O_WQKVT = 0;        // [288][96]
constexpr int O_WPROJT = 27648;   // [96][96]
constexpr int O_WFC1T = 36864;    // [384][96]
constexpr int O_WFC2T = 73728;    // [96][384]
constexpr int W_TOT = 110592;

__device__ __forceinline__ unsigned short f2b(float f) {
  return __builtin_bit_cast(unsigned short, __float2bfloat16(f));
}
__device__ __forceinline__ float b2f(unsigned short u) {
  return __bfloat162float(__builtin_bit_cast(__hip_bfloat16, u));
}

// Exact-GELU via Abramowitz-Stegun 7.1.26 erf (|eps| <= 1.5e-7).
__device__ __forceinline__ float gelu_f(float x) {
  float u = x * 0.70710678118654752f;
  float ax = __builtin_fabsf(u);
  float t = __builtin_amdgcn_rcpf(1.f + 0.3275911f * ax);
  float poly = t * (0.254829592f +
               t * (-0.284496736f +
               t * (1.421413741f +
               t * (-1.453152027f +
               t * 1.061405429f))));
  float erf_abs = 1.f - poly * __expf(-ax * ax);
  float erf_u = (u < 0.f) ? -erf_abs : erf_abs;
  return 0.5f * x * (1.f + erf_u);
}

// ---------------- weight transpose+cvt prep ----------------
__global__ void prep_weights(const float* __restrict__ wqkv,
                             const float* __restrict__ wproj,
                             const float* __restrict__ wfc1,
                             const float* __restrict__ wfc2,
                             unsigned short* __restrict__ ws) {
  int i = blockIdx.x * 256 + threadIdx.x;
  if (i >= W_TOT) return;
  float v;
  if (i < O_WPROJT) {
    int n = i / 96, k = i - n * 96;
    v = wqkv[k * 288 + n];
  } else if (i < O_WFC1T) {
    int j = i - O_WPROJT, n = j / 96, k = j - n * 96;
    v = wproj[k * 96 + n];
  } else if (i < O_WFC2T) {
    int j = i - O_WFC1T, n = j / 96, k = j - n * 96;
    v = wfc1[k * 384 + n];
  } else {
    int j = i - O_WFC2T, n = j / 384, k = j - n * 384;
    v = wfc2[k * 96 + n];
  }
  ws[i] = f2b(v);
}

// =====================================================================
// Kernel A (MFMA): one 8x8 window per block, 4 waves; wave = 16-row m-tile.
// ROUND-2 PROVEN VERSION (bisect: attn reverted, only mlp keeps the new
// launch bound). LN1 wave-private -> qkv -> LePE pass -> per-head attn
// (pS buffer, no in-loop barrier) -> proj. Barriers: 2.
// =====================================================================
__global__ __launch_bounds__(256, 2)
void attn_mfma(const float* __restrict__ x, const float* __restrict__ bqkv,
               const float* __restrict__ wlepe, const float* __restrict__ blepe,
               const float* __restrict__ bproj, const float* __restrict__ g1,
               const float* __restrict__ bt1,
               const unsigned short* __restrict__ ws, float* __restrict__ out) {
  constexpr int SA = 104;   // hA/O stride (bf16 elems); 208B, 16B-aligned
  constexpr int SQ = 200;   // qkS stride (q cols 0..95, k cols 96..191)
  constexpr int SV = 72;    // vS stride
  constexpr int SP = 72;    // pS stride
  __shared__ __attribute__((aligned(16))) unsigned short hA[64 * SA];   // h, LePE, then O
  __shared__ __attribute__((aligned(16))) unsigned short qkS[64 * SQ];
  __shared__ __attribute__((aligned(16))) unsigned short vS[96 * SV];
  __shared__ __attribute__((aligned(16))) unsigned short pS[64 * SP];

  const int tid = threadIdx.x, lane = tid & 63;
  const int wv = __builtin_amdgcn_readfirstlane(tid >> 6);
  const int w = blockIdx.x, b = w >> 6, wi = w & 63, wr = wi >> 3, wc = wi & 7;
  const long xbase = (long)b * (LTOK * CDIM);
  const int l15 = lane & 15, lk = (lane >> 4) * 8, lr = (lane >> 4) * 4;
  const int p = lane >> 4;            // channel quarter for LN phase
  const int tok = wv * 16 + l15;      // wave-private token for LN phase

  // ---- load + LN1 (wave-private tokens; shfl reduce; no barrier) ----
  {
    const long rowbase =
        xbase + (long)((wr * 8 + (tok >> 3)) * RDIM + wc * 8 + (tok & 7)) * CDIM;
    const float* rb = x + rowbase + p * 24;
    float xv[24], s1 = 0.f, s2 = 0.f;
#pragma unroll
    for (int i = 0; i < 6; ++i) {
      f32x4 v4 = *(const f32x4*)(rb + i * 4);
#pragma unroll
      for (int j = 0; j < 4; ++j) {
        float v = v4[j];
        xv[i * 4 + j] = v; s1 += v; s2 += v * v;
      }
    }
    s1 += __shfl_xor(s1, 16, 64); s1 += __shfl_xor(s1, 32, 64);
    s2 += __shfl_xor(s2, 16, 64); s2 += __shfl_xor(s2, 32, 64);
    float m = s1 * (1.f / 96.f);
    float vv = s2 * (1.f / 96.f) - m * m;
    float rs = rsqrtf(vv + 1e-5f);
    unsigned short tmp[24];
#pragma unroll
    for (int i = 0; i < 6; ++i) {
      f32x4 gv = *(const f32x4*)(g1 + p * 24 + i * 4);
      f32x4 bv = *(const f32x4*)(bt1 + p * 24 + i * 4);
#pragma unroll
      for (int j = 0; j < 4; ++j)
        tmp[i * 4 + j] = f2b((xv[i * 4 + j] - m) * rs * gv[j] + bv[j]);
    }
#pragma unroll
    for (int i = 0; i < 3; ++i)
      *(short8*)&hA[tok * SA + p * 24 + i * 8] = *(const short8*)&tmp[i * 8];
  }
  // NO barrier: qkv below reads only this wave's own hA rows.

  // ---- qkv: wave's 16 rows x 288 cols ----
  {
    f32x4 acc[18];
#pragma unroll
    for (int t = 0; t < 18; ++t) acc[t] = (f32x4){0.f, 0.f, 0.f, 0.f};
    const int arow = wv * 16 + l15;
    __builtin_amdgcn_s_setprio(1);
#pragma unroll
    for (int kk = 0; kk < 3; ++kk) {
      short8 a = *(const short8*)&hA[arow * SA + kk * 32 + lk];
#pragma unroll
      for (int nt = 0; nt < 18; ++nt) {
        short8 bw = *(const short8*)&ws[O_WQKVT + (nt * 16 + l15) * 96 + kk * 32 + lk];
        acc[nt] = __builtin_amdgcn_mfma_f32_16x16x32_bf16(a, bw, acc[nt], 0, 0, 0);
      }
    }
    __builtin_amdgcn_s_setprio(0);
    // stage q (scaled), k, v with bias
#pragma unroll
    for (int nt = 0; nt < 18; ++nt) {
      int n0 = nt * 16 + l15;
      float bias = bqkv[n0];
#pragma unroll
      for (int r = 0; r < 4; ++r) {
        int tk = wv * 16 + lr + r;
        float v = acc[nt][r] + bias;
        if (n0 < 96) qkS[tk * SQ + n0] = f2b(v * SCALE);
        else if (n0 < 192) qkS[tk * SQ + n0] = f2b(v);
        else vS[(n0 - 192) * SV + tk] = f2b(v);
      }
    }
  }
  __syncthreads();   // barrier A: k/v staged by all waves

  // ---- LePE pass: thread = (channel, 4-spatial-row strip). vS rows of 8
  //      tokens are contiguous 16B -> ds_read_b128; conv fully in regs.
  //      Result parked in hA (h is dead: each wave consumed its own rows).
  if (tid < 192) {
    const int c = tid >> 1;       // 0..95
    const int half = tid & 1;     // rows 0-3 / 4-7
    const int r0 = half * 4;
    float rowb[6][8];
#pragma unroll
    for (int rr = 0; rr < 6; ++rr) {
      int vr = r0 - 1 + rr;
      if (vr >= 0 && vr < 8) {
        short8 v8 = *(const short8*)&vS[c * SV + vr * 8];
#pragma unroll
        for (int j = 0; j < 8; ++j) rowb[rr][j] = b2f((unsigned short)v8[j]);
      } else {
#pragma unroll
        for (int j = 0; j < 8; ++j) rowb[rr][j] = 0.f;
      }
    }
    float lw9[9];
#pragma unroll
    for (int q = 0; q < 9; ++q) lw9[q] = wlepe[c * 9 + q];
    const float lb = blepe[c];
#pragma unroll
    for (int r = 0; r < 4; ++r) {
#pragma unroll
      for (int cc = 0; cc < 8; ++cc) {
        float a = lb;
#pragma unroll
        for (int kh = 0; kh < 3; ++kh) {
          const float* rbp = rowb[r + kh];
          if (cc > 0) a += lw9[kh * 3 + 0] * rbp[cc - 1];
          a += lw9[kh * 3 + 1] * rbp[cc];
          if (cc < 7) a += lw9[kh * 3 + 2] * rbp[cc + 1];
        }
        hA[((r0 + r) * 8 + cc) * SA + c] = f2b(a);
      }
    }
  }
  __syncthreads();   // barrier B: LePE parked in hA

  // ---- per-head attention ----
  for (int h = 0; h < NH_; ++h) {
    f32x4 sacc[4];
#pragma unroll
    for (int t = 0; t < 4; ++t) sacc[t] = (f32x4){0.f, 0.f, 0.f, 0.f};
    short8 aq = *(const short8*)&qkS[(wv * 16 + l15) * SQ + h * 32 + lk];
#pragma unroll
    for (int nt = 0; nt < 4; ++nt) {
      short8 bk = *(const short8*)&qkS[(nt * 16 + l15) * SQ + 96 + h * 32 + lk];
      sacc[nt] = __builtin_amdgcn_mfma_f32_16x16x32_bf16(aq, bk, sacc[nt], 0, 0, 0);
    }
    // softmax (rows live in 16-lane groups)
    float pr[4][4];
#pragma unroll
    for (int r = 0; r < 4; ++r) {
      float mx = -1e30f;
#pragma unroll
      for (int nt = 0; nt < 4; ++nt) mx = fmaxf(mx, sacc[nt][r]);
#pragma unroll
      for (int s = 1; s < 16; s <<= 1) mx = fmaxf(mx, __shfl_xor(mx, s, 64));
      float sum = 0.f;
#pragma unroll
      for (int nt = 0; nt < 4; ++nt) {
        float e = __expf(sacc[nt][r] - mx);
        pr[nt][r] = e; sum += e;
      }
#pragma unroll
      for (int s = 1; s < 16; s <<= 1) sum += __shfl_xor(sum, s, 64);
      float inv = 1.f / sum;
#pragma unroll
      for (int nt = 0; nt < 4; ++nt) pr[nt][r] *= inv;
    }
    // write attn probs (fp32) + stage P (bf16, wave-local rows)
    const long o1base = OUT1OFF + ((long)(w * NH_ + h) * GG) * GG;
#pragma unroll
    for (int nt = 0; nt < 4; ++nt) {
      int col = nt * 16 + l15;
#pragma unroll
      for (int r = 0; r < 4; ++r) {
        int row = wv * 16 + lr + r;
        out[o1base + (long)row * GG + col] = pr[nt][r];
        pS[row * SP + col] = f2b(pr[nt][r]);
      }
    }
    // PV (same wave produced pS rows; vS covered by barrier A)
    f32x4 oa[2];
    oa[0] = (f32x4){0.f, 0.f, 0.f, 0.f};
    oa[1] = (f32x4){0.f, 0.f, 0.f, 0.f};
#pragma unroll
    for (int kk = 0; kk < 2; ++kk) {
      short8 ap = *(const short8*)&pS[(wv * 16 + l15) * SP + kk * 32 + lk];
#pragma unroll
      for (int nt = 0; nt < 2; ++nt) {
        short8 bv = *(const short8*)&vS[(h * 32 + nt * 16 + l15) * SV + kk * 32 + lk];
        oa[nt] = __builtin_amdgcn_mfma_f32_16x16x32_bf16(ap, bv, oa[nt], 0, 0, 0);
      }
    }
    // O = PV + LePE (read parked LePE from hA, overwrite in place)
#pragma unroll
    for (int nt = 0; nt < 2; ++nt) {
      int c = h * 32 + nt * 16 + l15;
#pragma unroll
      for (int r = 0; r < 4; ++r) {
        int tk = wv * 16 + lr + r;
        hA[tk * SA + c] = f2b(oa[nt][r] + b2f(hA[tk * SA + c]));
      }
    }
  }
  // NO barrier: proj reads only this wave's own hA rows (all written above).

  // ---- proj + residual epilogue ----
  {
    f32x4 pacc[6];
#pragma unroll
    for (int t = 0; t < 6; ++t) pacc[t] = (f32x4){0.f, 0.f, 0.f, 0.f};
    __builtin_amdgcn_s_setprio(1);
#pragma unroll
    for (int kk = 0; kk < 3; ++kk) {
      short8 ao = *(const short8*)&hA[(wv * 16 + l15) * SA + kk * 32 + lk];
#pragma unroll
      for (int nt = 0; nt < 6; ++nt) {
        short8 bw = *(const short8*)&ws[O_WPROJT + (nt * 16 + l15) * 96 + kk * 32 + lk];
        pacc[nt] = __builtin_amdgcn_mfma_f32_16x16x32_bf16(ao, bw, pacc[nt], 0, 0, 0);
      }
    }
    __builtin_amdgcn_s_setprio(0);
#pragma unroll
    for (int nt = 0; nt < 6; ++nt) {
      int ch = nt * 16 + l15;
      float bias = bproj[ch];
#pragma unroll
      for (int r = 0; r < 4; ++r) {
        int tk = wv * 16 + lr + r;
        long g = xbase + (long)((wr * 8 + (tk >> 3)) * RDIM + wc * 8 + (tk & 7)) * CDIM + ch;
        out[g] = x[g] + pacc[nt][r] + bias;
      }
    }
  }
}

// =====================================================================
// Kernel B (MFMA): 64 tokens per block, 4 waves, wave-private everything.
// BISECT DELTA: launch_bounds(256,6) -> 6 blocks/CU (LDS 6*26624 = 159744
// fits the 160 KiB pool; VGPR 60 < 85 cap). Everything else = round 2.
// =====================================================================
__global__ __launch_bounds__(256, 6)
void mlp_mfma(const float* __restrict__ bfc1, const float* __restrict__ bfc2,
              const float* __restrict__ g2, const float* __restrict__ bt2,
              const unsigned short* __restrict__ ws, float* __restrict__ out) {
  constexpr int SB = 104;
  constexpr int SHQ = 104;
  __shared__ __attribute__((aligned(16))) unsigned short hB[64 * SB];
  __shared__ __attribute__((aligned(16))) unsigned short Hq[64 * SHQ];

  const int tid = threadIdx.x, lane = tid & 63;
  const int wv = __builtin_amdgcn_readfirstlane(tid >> 6);
  const long t0 = (long)blockIdx.x * GG;
  const int l15 = lane & 15, lk = (lane >> 4) * 8, lr = (lane >> 4) * 4;
  const int p = lane >> 4;
  const int tok = wv * 16 + l15;

  {
    const float* rb = out + (t0 + tok) * CDIM + p * 24;
    float xv[24], s1 = 0.f, s2 = 0.f;
#pragma unroll
    for (int i = 0; i < 6; ++i) {
      f32x4 v4 = *(const f32x4*)(rb + i * 4);
#pragma unroll
      for (int j = 0; j < 4; ++j) {
        float v = v4[j];
        xv[i * 4 + j] = v; s1 += v; s2 += v * v;
      }
    }
    s1 += __shfl_xor(s1, 16, 64); s1 += __shfl_xor(s1, 32, 64);
    s2 += __shfl_xor(s2, 16, 64); s2 += __shfl_xor(s2, 32, 64);
    float m = s1 * (1.f / 96.f);
    float vv = s2 * (1.f / 96.f) - m * m;
    float rs = rsqrtf(vv + 1e-5f);
    unsigned short tmp[24];
#pragma unroll
    for (int i = 0; i < 24; ++i) {
      int c = p * 24 + i;
      tmp[i] = f2b((xv[i] - m) * rs * g2[c] + bt2[c]);
    }
#pragma unroll
    for (int i = 0; i < 3; ++i)
      *(short8*)&hB[tok * SB + p * 24 + i * 8] = *(const short8*)&tmp[i * 8];
  }

  f32x4 acc2[6];
#pragma unroll
  for (int t = 0; t < 6; ++t) acc2[t] = (f32x4){0.f, 0.f, 0.f, 0.f};

#pragma unroll 1
  for (int q = 0; q < 4; ++q) {
    f32x4 acc1[6];
#pragma unroll
    for (int t = 0; t < 6; ++t) acc1[t] = (f32x4){0.f, 0.f, 0.f, 0.f};
#pragma unroll
    for (int kk = 0; kk < 3; ++kk) {
      short8 a = *(const short8*)&hB[(wv * 16 + l15) * SB + kk * 32 + lk];
#pragma unroll
      for (int nt = 0; nt < 6; ++nt) {
        int n = q * 96 + nt * 16 + l15;
        short8 bw = *(const short8*)&ws[O_WFC1T + n * 96 + kk * 32 + lk];
        acc1[nt] = __builtin_amdgcn_mfma_f32_16x16x32_bf16(a, bw, acc1[nt], 0, 0, 0);
      }
    }
#pragma unroll
    for (int nt = 0; nt < 6; ++nt) {
      int n = q * 96 + nt * 16 + l15;
      float bias = bfc1[n];
#pragma unroll
      for (int r = 0; r < 4; ++r) {
        int tk = wv * 16 + lr + r;
        Hq[tk * SHQ + nt * 16 + l15] = f2b(gelu_f(acc1[nt][r] + bias));
      }
    }
#pragma unroll
    for (int kk = 0; kk < 3; ++kk) {
      short8 a = *(const short8*)&Hq[(wv * 16 + l15) * SHQ + kk * 32 + lk];
#pragma unroll
      for (int nt = 0; nt < 6; ++nt) {
        short8 bw = *(const short8*)&ws[O_WFC2T + (nt * 16 + l15) * 384 + q * 96 + kk * 32 + lk];
        acc2[nt] = __builtin_amdgcn_mfma_f32_16x16x32_bf16(a, bw, acc2[nt], 0, 0, 0);
      }
    }
  }

#pragma unroll
  for (int nt = 0; nt < 6; ++nt) {
    int ch = nt * 16 + l15;
    float bias = bfc2[ch];
#pragma unroll
    for (int r = 0; r < 4; ++r) {
      int tk = wv * 16 + lr + r;
      long g = (t0 + tk) * CDIM + ch;
      out[g] = out[g] + acc2[nt][r] + bias;
    }
  }
}

// =====================================================================
// Scalar fallback (round-2 proven path), used only if ws too small.
// =====================================================================
struct PF {
  const float *x, *w_qkv, *b_qkv, *w_lepe, *b_lepe, *w_proj, *b_proj;
  const float *g1, *bt1, *g2, *bt2, *w_fc1, *b_fc1, *w_fc2, *b_fc2;
  float* out;
};

__global__ __launch_bounds__(256, 2)
void attn_scalar(PF p) {
  constexpr int SA = 66;
  __shared__ __hip_bfloat16 bufA[CDIM * SA];
  __shared__ __hip_bfloat16 qkvT[288 * GG];
  __shared__ __hip_bfloat16 sPad[GG * SA];
  __shared__ float meanS[GG], rstdS[GG];

  const int w = blockIdx.x;
  const int b = w >> 6, wi = w & 63, wr = wi >> 3, wc = wi & 7;
  const int tid = threadIdx.x, lane = tid & 63;
  const int wv = __builtin_amdgcn_readfirstlane(tid >> 6);
  const long xbase = (long)b * (LTOK * CDIM);

  for (int k = 0; k < 24; ++k) {
    int e = tid + k * 256, wrow = e / 768, o = e - wrow * 768;
    int tir = o / 96, ch = o - tir * 96;
    long g = xbase + ((wr * 8 + wrow) * RDIM + wc * 8 + tir) * CDIM + ch;
    bufA[ch * SA + wrow * 8 + tir] = __float2bfloat16(p.x[g]);
  }
  __syncthreads();
  if (wv == 0) {
    float m = 0.f;
    for (int c = 0; c < CDIM; ++c) m += __bfloat162float(bufA[c * SA + lane]);
    m *= (1.f / CDIM);
    float var = 0.f;
    for (int c = 0; c < CDIM; ++c) {
      float d = __bfloat162float(bufA[c * SA + lane]) - m;
      var += d * d;
    }
    meanS[lane] = m;
    rstdS[lane] = rsqrtf(var * (1.f / CDIM) + 1e-5f);
  }
  __syncthreads();
  {
    float m = meanS[lane], rs = rstdS[lane];
    for (int cc = 0; cc < 24; ++cc) {
      int c = wv * 24 + cc;
      float v = __bfloat162float(bufA[c * SA + lane]);
      bufA[c * SA + lane] = __float2bfloat16((v - m) * rs * p.g1[c] + p.bt1[c]);
    }
  }
  __syncthreads();
  for (int tile = 0; tile < 2; ++tile) {
    int j0 = wv * 72 + tile * 36;
    float acc[36];
#pragma unroll
    for (int jj = 0; jj < 36; ++jj) acc[jj] = p.b_qkv[j0 + jj];
#pragma unroll 1
    for (int c = 0; c < CDIM; ++c) {
      float hv = __bfloat162float(bufA[c * SA + lane]);
#pragma unroll
      for (int jj = 0; jj < 36; ++jj) acc[jj] += hv * p.w_qkv[c * 288 + j0 + jj];
    }
#pragma unroll
    for (int jj = 0; jj < 36; ++jj)
      qkvT[(j0 + jj) * GG + lane] = __float2bfloat16(acc[jj]);
  }
  __syncthreads();
  for (int hh = 0; hh < NH_; ++hh) {
    float kreg[HD_];
#pragma unroll
    for (int d = 0; d < HD_; ++d)
      kreg[d] = __bfloat162float(qkvT[(CDIM + hh * HD_ + d) * GG + lane]);
#pragma unroll 1
    for (int r = 0; r < 16; ++r) {
      int i = wv * 16 + r;
      float acc = 0.f;
#pragma unroll
      for (int d = 0; d < HD_; ++d)
        acc += __bfloat162float(qkvT[(hh * HD_ + d) * GG + i]) * kreg[d];
      sPad[lane * SA + i] = __float2bfloat16(acc * SCALE);
    }
#pragma unroll 1
    for (int r = 0; r < 16; ++r) {
      int i = wv * 16 + r;
      float v = __bfloat162float(sPad[lane * SA + i]);
      float mx = v;
#pragma unroll
      for (int s = 32; s > 0; s >>= 1) mx = fmaxf(mx, __shfl_xor(mx, s, 64));
      float e = __expf(v - mx);
      float sum = e;
#pragma unroll
      for (int s = 32; s > 0; s >>= 1) sum += __shfl_xor(sum, s, 64);
      float rr = e / sum;
      sPad[lane * SA + i] = __float2bfloat16(rr);
      p.out[OUT1OFF + ((long)(w * NH_ + hh) * GG + i) * GG + lane] = rr;
    }
    __syncthreads();
    {
      int d0 = wv * 8;
      float acc[8];
#pragma unroll
      for (int dd = 0; dd < 8; ++dd) acc[dd] = 0.f;
#pragma unroll 1
      for (int j = 0; j < GG; ++j) {
        float sv = __bfloat162float(sPad[j * SA + lane]);
#pragma unroll
        for (int dd = 0; dd < 8; ++dd)
          acc[dd] += sv * __bfloat162float(qkvT[(2 * CDIM + hh * HD_ + d0 + dd) * GG + j]);
      }
      int tr = lane >> 3, tc = lane & 7;
#pragma unroll
      for (int dd = 0; dd < 8; ++dd) {
        int c = hh * HD_ + d0 + dd;
        float a = p.b_lepe[c];
#pragma unroll
        for (int kh = 0; kh < 3; ++kh)
#pragma unroll
          for (int kw = 0; kw < 3; ++kw) {
            int rr2 = tr + kh - 1, cc2 = tc + kw - 1;
            if (rr2 >= 0 && rr2 < 8 && cc2 >= 0 && cc2 < 8)
              a += p.w_lepe[c * 9 + kh * 3 + kw] *
                   __bfloat162float(qkvT[(2 * CDIM + hh * HD_ + d0 + dd) * GG + rr2 * 8 + cc2]);
          }
        acc[dd] += a;
      }
#pragma unroll
      for (int dd = 0; dd < 8; ++dd)
        bufA[(hh * HD_ + d0 + dd) * SA + lane] = __float2bfloat16(acc[dd]);
    }
    __syncthreads();
  }
  __hip_bfloat16* projT = qkvT;
  {
    int j0 = wv * 24;
    float acc[24];
#pragma unroll
    for (int jj = 0; jj < 24; ++jj) acc[jj] = p.b_proj[j0 + jj];
#pragma unroll 1
    for (int c = 0; c < CDIM; ++c) {
      float ov = __bfloat162float(bufA[c * SA + lane]);
#pragma unroll
      for (int jj = 0; jj < 24; ++jj) acc[jj] += ov * p.w_proj[c * CDIM + j0 + jj];
    }
#pragma unroll
    for (int jj = 0; jj < 24; ++jj)
      projT[(j0 + jj) * SA + lane] = __float2bfloat16(acc[jj]);
  }
  __syncthreads();
  for (int k = 0; k < 24; ++k) {
    int e = tid + k * 256, wrow = e / 768, o = e - wrow * 768;
    int tir = o / 96, ch = o - tir * 96;
    long g = xbase + ((wr * 8 + wrow) * RDIM + wc * 8 + tir) * CDIM + ch;
    p.out[g] = p.x[g] + __bfloat162float(projT[ch * SA + wrow * 8 + tir]);
  }
}

__global__ __launch_bounds__(256, 2)
void mlp_scalar(PF p) {
  constexpr int SB = 66;
  __shared__ __hip_bfloat16 bufB[CDIM * SB];
  __shared__ __hip_bfloat16 hidT[HID * GG];
  __shared__ float meanS[GG], rstdS[GG];

  const int tid = threadIdx.x, lane = tid & 63;
  const int wv = __builtin_amdgcn_readfirstlane(tid >> 6);
  const long t0 = (long)blockIdx.x * GG;

  for (int k = 0; k < 24; ++k) {
    int e = tid + k * 256, tok = e / 96, ch = e - tok * 96;
    bufB[ch * SB + tok] = __float2bfloat16(p.out[(t0 + tok) * CDIM + ch]);
  }
  __syncthreads();
  if (wv == 0) {
    float m = 0.f;
    for (int c = 0; c < CDIM; ++c) m += __bfloat162float(bufB[c * SB + lane]);
    m *= (1.f / CDIM);
    float var = 0.f;
    for (int c = 0; c < CDIM; ++c) {
      float d = __bfloat162float(bufB[c * SB + lane]) - m;
      var += d * d;
    }
    meanS[lane] = m;
    rstdS[lane] = rsqrtf(var * (1.f / CDIM) + 1e-5f);
  }
  __syncthreads();
  {
    float m = meanS[lane], rs = rstdS[lane];
    for (int cc = 0; cc < 24; ++cc) {
      int c = wv * 24 + cc;
      float v = __bfloat162float(bufB[c * SB + lane]);
      bufB[c * SB + lane] = __float2bfloat16((v - m) * rs * p.g2[c] + p.bt2[c]);
    }
  }
  __syncthreads();
  for (int tile = 0; tile < 4; ++tile) {
    int j0 = wv * 96 + tile * 24;
    float acc[24];
#pragma unroll
    for (int jj = 0; jj < 24; ++jj) acc[jj] = p.b_fc1[j0 + jj];
#pragma unroll 1
    for (int c = 0; c < CDIM; ++c) {
      float hv = __bfloat162float(bufB[c * SB + lane]);
#pragma unroll
      for (int jj = 0; jj < 24; ++jj) acc[jj] += hv * p.w_fc1[c * HID + j0 + jj];
    }
#pragma unroll
    for (int jj = 0; jj < 24; ++jj) {
      float xg = acc[jj];
      hidT[(j0 + jj) * GG + lane] =
          __float2bfloat16(0.5f * xg * (1.f + erff(xg * 0.70710678118f)));
    }
  }
  __syncthreads();
  {
    int j0 = wv * 24;
    float acc[24];
#pragma unroll
    for (int jj = 0; jj < 24; ++jj) acc[jj] = p.b_fc2[j0 + jj];
#pragma unroll 1
    for (int h = 0; h < HID; ++h) {
      float hv = __bfloat162float(hidT[h * GG + lane]);
#pragma unroll
      for (int jj = 0; jj < 24; ++jj) acc[jj] += hv * p.w_fc2[h * CDIM + j0 + jj];
    }
#pragma unroll
    for (int jj = 0; jj < 24; ++jj)
      bufB[(j0 + jj) * SB + lane] = __float2bfloat16(acc[jj]);
  }
  __syncthreads();
  for (int k = 0; k < 24; ++k) {
    int e = tid + k * 256, tok = e / 96, ch = e - tok * 96;
    long g = (t0 + tok) * CDIM + ch;
    p.out[g] = p.out[g] + __bfloat162float(bufB[ch * SB + tok]);
  }
}

extern "C" void kernel_launch(void* const* d_in, const int* in_sizes, int n_in,
                              void* d_out, int out_size, void* d_ws, size_t ws_size,
                              hipStream_t stream) {
  const float* x = (const float*)d_in[0];
  const float* w_qkv = (const float*)d_in[1];
  const float* b_qkv = (const float*)d_in[2];
  const float* w_lepe = (const float*)d_in[3];
  const float* b_lepe = (const float*)d_in[4];
  const float* w_proj = (const float*)d_in[5];
  const float* b_proj = (const float*)d_in[6];
  const float* g1 = (const float*)d_in[7];
  const float* bt1 = (const float*)d_in[8];
  const float* g2 = (const float*)d_in[9];
  const float* bt2 = (const float*)d_in[10];
  const float* w_fc1 = (const float*)d_in[11];
  const float* b_fc1 = (const float*)d_in[12];
  const float* w_fc2 = (const float*)d_in[13];
  const float* b_fc2 = (const float*)d_in[14];
  float* out = (float*)d_out;
  const int mlp_blocks = (BDIM * LTOK) / GG;  // 2048

  if (ws_size >= (size_t)W_TOT * sizeof(unsigned short)) {
    unsigned short* ws = (unsigned short*)d_ws;
    prep_weights<<<(W_TOT + 255) / 256, 256, 0, stream>>>(w_qkv, w_proj, w_fc1, w_fc2, ws);
    attn_mfma<<<NWIN, 256, 0, stream>>>(x, b_qkv, w_lepe, b_lepe, b_proj, g1, bt1, ws, out);
    mlp_mfma<<<mlp_blocks, 256, 0, stream>>>(b_fc1, b_fc2, g2, bt2, ws, out);
  } else {
    PF p{x, w_qkv, b_qkv, w_lepe, b_lepe, w_proj, b_proj,
         g1, bt1, g2, bt2, w_fc1, b_fc1, w_fc2, b_fc2, out};
    attn_scalar<<<NWIN, 256, 0, stream>>>(p);
    mlp_scalar<<<mlp_blocks, 256, 0, stream>>>(p);
  }
}

// Round 6
// 389.755 us; speedup vs baseline: 1.1163x; 1.1163x over previous
//
#include <hip/hip_runtime.h>
#include <hip/hip_bf16.h>

typedef short short8 __attribute__((ext_vector_type(8)));
typedef float f32x4 __attribute__((ext_vector_type(4)));

constexpr int BDIM = 32, RDIM = 64, CDIM = 96, NH_ = 3, HD_ = 32;
constexpr int LTOK = RDIM * RDIM;      // 4096
constexpr int GG = 64;
constexpr int HID = 384;
constexpr int NWIN = 2048;
constexpr float SCALE = 0.17677669529663687f;
constexpr long OUT1OFF = (long)BDIM * LTOK * CDIM;   // 12582912

// ws layout (bf16 element offsets): transposed weights [n][k], k-contiguous
constexpr int O_WQKVT = 0;        // [288][96]
constexpr int O_WPROJT = 27648;   // [96][96]
constexpr int O_WFC1T = 36864;    // [384][96]
constexpr int O_WFC2T = 73728;    // [96][384]
constexpr int W_TOT = 110592;

__device__ __forceinline__ unsigned short f2b(float f) {
  return __builtin_bit_cast(unsigned short, __float2bfloat16(f));
}
__device__ __forceinline__ float b2f(unsigned short u) {
  return __bfloat162float(__builtin_bit_cast(__hip_bfloat16, u));
}

// Exact-GELU via Abramowitz-Stegun 7.1.26 erf (|eps| <= 1.5e-7).
__device__ __forceinline__ float gelu_f(float x) {
  float u = x * 0.70710678118654752f;
  float ax = __builtin_fabsf(u);
  float t = __builtin_amdgcn_rcpf(1.f + 0.3275911f * ax);
  float poly = t * (0.254829592f +
               t * (-0.284496736f +
               t * (1.421413741f +
               t * (-1.453152027f +
               t * 1.061405429f))));
  float erf_abs = 1.f - poly * __expf(-ax * ax);
  float erf_u = (u < 0.f) ? -erf_abs : erf_abs;
  return 0.5f * x * (1.f + erf_u);
}

// ---------------- weight transpose+cvt prep ----------------
__global__ void prep_weights(const float* __restrict__ wqkv,
                             const float* __restrict__ wproj,
                             const float* __restrict__ wfc1,
                             const float* __restrict__ wfc2,
                             unsigned short* __restrict__ ws) {
  int i = blockIdx.x * 256 + threadIdx.x;
  if (i >= W_TOT) return;
  float v;
  if (i < O_WPROJT) {
    int n = i / 96, k = i - n * 96;
    v = wqkv[k * 288 + n];
  } else if (i < O_WFC1T) {
    int j = i - O_WPROJT, n = j / 96, k = j - n * 96;
    v = wproj[k * 96 + n];
  } else if (i < O_WFC2T) {
    int j = i - O_WFC1T, n = j / 96, k = j - n * 96;
    v = wfc1[k * 384 + n];
  } else {
    int j = i - O_WFC2T, n = j / 384, k = j - n * 384;
    v = wfc2[k * 96 + n];
  }
  ws[i] = f2b(v);
}

// =====================================================================
// Kernel A (MFMA): one 8x8 window per block, 4 waves; wave = 16-row m-tile.
// ROUND-2 PROVEN VERSION (untouched). LN1 wave-private -> qkv -> LePE pass
// -> per-head attn (pS buffer, no in-loop barrier) -> proj. Barriers: 2.
// =====================================================================
__global__ __launch_bounds__(256, 2)
void attn_mfma(const float* __restrict__ x, const float* __restrict__ bqkv,
               const float* __restrict__ wlepe, const float* __restrict__ blepe,
               const float* __restrict__ bproj, const float* __restrict__ g1,
               const float* __restrict__ bt1,
               const unsigned short* __restrict__ ws, float* __restrict__ out) {
  constexpr int SA = 104;   // hA/O stride (bf16 elems); 208B, 16B-aligned
  constexpr int SQ = 200;   // qkS stride (q cols 0..95, k cols 96..191)
  constexpr int SV = 72;    // vS stride
  constexpr int SP = 72;    // pS stride
  __shared__ __attribute__((aligned(16))) unsigned short hA[64 * SA];   // h, LePE, then O
  __shared__ __attribute__((aligned(16))) unsigned short qkS[64 * SQ];
  __shared__ __attribute__((aligned(16))) unsigned short vS[96 * SV];
  __shared__ __attribute__((aligned(16))) unsigned short pS[64 * SP];

  const int tid = threadIdx.x, lane = tid & 63;
  const int wv = __builtin_amdgcn_readfirstlane(tid >> 6);
  const int w = blockIdx.x, b = w >> 6, wi = w & 63, wr = wi >> 3, wc = wi & 7;
  const long xbase = (long)b * (LTOK * CDIM);
  const int l15 = lane & 15, lk = (lane >> 4) * 8, lr = (lane >> 4) * 4;
  const int p = lane >> 4;            // channel quarter for LN phase
  const int tok = wv * 16 + l15;      // wave-private token for LN phase

  // ---- load + LN1 (wave-private tokens; shfl reduce; no barrier) ----
  {
    const long rowbase =
        xbase + (long)((wr * 8 + (tok >> 3)) * RDIM + wc * 8 + (tok & 7)) * CDIM;
    const float* rb = x + rowbase + p * 24;
    float xv[24], s1 = 0.f, s2 = 0.f;
#pragma unroll
    for (int i = 0; i < 6; ++i) {
      f32x4 v4 = *(const f32x4*)(rb + i * 4);
#pragma unroll
      for (int j = 0; j < 4; ++j) {
        float v = v4[j];
        xv[i * 4 + j] = v; s1 += v; s2 += v * v;
      }
    }
    s1 += __shfl_xor(s1, 16, 64); s1 += __shfl_xor(s1, 32, 64);
    s2 += __shfl_xor(s2, 16, 64); s2 += __shfl_xor(s2, 32, 64);
    float m = s1 * (1.f / 96.f);
    float vv = s2 * (1.f / 96.f) - m * m;
    float rs = rsqrtf(vv + 1e-5f);
    unsigned short tmp[24];
#pragma unroll
    for (int i = 0; i < 6; ++i) {
      f32x4 gv = *(const f32x4*)(g1 + p * 24 + i * 4);
      f32x4 bv = *(const f32x4*)(bt1 + p * 24 + i * 4);
#pragma unroll
      for (int j = 0; j < 4; ++j)
        tmp[i * 4 + j] = f2b((xv[i * 4 + j] - m) * rs * gv[j] + bv[j]);
    }
#pragma unroll
    for (int i = 0; i < 3; ++i)
      *(short8*)&hA[tok * SA + p * 24 + i * 8] = *(const short8*)&tmp[i * 8];
  }
  // NO barrier: qkv below reads only this wave's own hA rows.

  // ---- qkv: wave's 16 rows x 288 cols ----
  {
    f32x4 acc[18];
#pragma unroll
    for (int t = 0; t < 18; ++t) acc[t] = (f32x4){0.f, 0.f, 0.f, 0.f};
    const int arow = wv * 16 + l15;
    __builtin_amdgcn_s_setprio(1);
#pragma unroll
    for (int kk = 0; kk < 3; ++kk) {
      short8 a = *(const short8*)&hA[arow * SA + kk * 32 + lk];
#pragma unroll
      for (int nt = 0; nt < 18; ++nt) {
        short8 bw = *(const short8*)&ws[O_WQKVT + (nt * 16 + l15) * 96 + kk * 32 + lk];
        acc[nt] = __builtin_amdgcn_mfma_f32_16x16x32_bf16(a, bw, acc[nt], 0, 0, 0);
      }
    }
    __builtin_amdgcn_s_setprio(0);
    // stage q (scaled), k, v with bias
#pragma unroll
    for (int nt = 0; nt < 18; ++nt) {
      int n0 = nt * 16 + l15;
      float bias = bqkv[n0];
#pragma unroll
      for (int r = 0; r < 4; ++r) {
        int tk = wv * 16 + lr + r;
        float v = acc[nt][r] + bias;
        if (n0 < 96) qkS[tk * SQ + n0] = f2b(v * SCALE);
        else if (n0 < 192) qkS[tk * SQ + n0] = f2b(v);
        else vS[(n0 - 192) * SV + tk] = f2b(v);
      }
    }
  }
  __syncthreads();   // barrier A: k/v staged by all waves

  // ---- LePE pass: thread = (channel, 4-spatial-row strip). vS rows of 8
  //      tokens are contiguous 16B -> ds_read_b128; conv fully in regs.
  //      Result parked in hA (h is dead: each wave consumed its own rows).
  if (tid < 192) {
    const int c = tid >> 1;       // 0..95
    const int half = tid & 1;     // rows 0-3 / 4-7
    const int r0 = half * 4;
    float rowb[6][8];
#pragma unroll
    for (int rr = 0; rr < 6; ++rr) {
      int vr = r0 - 1 + rr;
      if (vr >= 0 && vr < 8) {
        short8 v8 = *(const short8*)&vS[c * SV + vr * 8];
#pragma unroll
        for (int j = 0; j < 8; ++j) rowb[rr][j] = b2f((unsigned short)v8[j]);
      } else {
#pragma unroll
        for (int j = 0; j < 8; ++j) rowb[rr][j] = 0.f;
      }
    }
    float lw9[9];
#pragma unroll
    for (int q = 0; q < 9; ++q) lw9[q] = wlepe[c * 9 + q];
    const float lb = blepe[c];
#pragma unroll
    for (int r = 0; r < 4; ++r) {
#pragma unroll
      for (int cc = 0; cc < 8; ++cc) {
        float a = lb;
#pragma unroll
        for (int kh = 0; kh < 3; ++kh) {
          const float* rbp = rowb[r + kh];
          if (cc > 0) a += lw9[kh * 3 + 0] * rbp[cc - 1];
          a += lw9[kh * 3 + 1] * rbp[cc];
          if (cc < 7) a += lw9[kh * 3 + 2] * rbp[cc + 1];
        }
        hA[((r0 + r) * 8 + cc) * SA + c] = f2b(a);
      }
    }
  }
  __syncthreads();   // barrier B: LePE parked in hA

  // ---- per-head attention ----
  for (int h = 0; h < NH_; ++h) {
    f32x4 sacc[4];
#pragma unroll
    for (int t = 0; t < 4; ++t) sacc[t] = (f32x4){0.f, 0.f, 0.f, 0.f};
    short8 aq = *(const short8*)&qkS[(wv * 16 + l15) * SQ + h * 32 + lk];
#pragma unroll
    for (int nt = 0; nt < 4; ++nt) {
      short8 bk = *(const short8*)&qkS[(nt * 16 + l15) * SQ + 96 + h * 32 + lk];
      sacc[nt] = __builtin_amdgcn_mfma_f32_16x16x32_bf16(aq, bk, sacc[nt], 0, 0, 0);
    }
    // softmax (rows live in 16-lane groups)
    float pr[4][4];
#pragma unroll
    for (int r = 0; r < 4; ++r) {
      float mx = -1e30f;
#pragma unroll
      for (int nt = 0; nt < 4; ++nt) mx = fmaxf(mx, sacc[nt][r]);
#pragma unroll
      for (int s = 1; s < 16; s <<= 1) mx = fmaxf(mx, __shfl_xor(mx, s, 64));
      float sum = 0.f;
#pragma unroll
      for (int nt = 0; nt < 4; ++nt) {
        float e = __expf(sacc[nt][r] - mx);
        pr[nt][r] = e; sum += e;
      }
#pragma unroll
      for (int s = 1; s < 16; s <<= 1) sum += __shfl_xor(sum, s, 64);
      float inv = 1.f / sum;
#pragma unroll
      for (int nt = 0; nt < 4; ++nt) pr[nt][r] *= inv;
    }
    // write attn probs (fp32) + stage P (bf16, wave-local rows)
    const long o1base = OUT1OFF + ((long)(w * NH_ + h) * GG) * GG;
#pragma unroll
    for (int nt = 0; nt < 4; ++nt) {
      int col = nt * 16 + l15;
#pragma unroll
      for (int r = 0; r < 4; ++r) {
        int row = wv * 16 + lr + r;
        out[o1base + (long)row * GG + col] = pr[nt][r];
        pS[row * SP + col] = f2b(pr[nt][r]);
      }
    }
    // PV (same wave produced pS rows; vS covered by barrier A)
    f32x4 oa[2];
    oa[0] = (f32x4){0.f, 0.f, 0.f, 0.f};
    oa[1] = (f32x4){0.f, 0.f, 0.f, 0.f};
#pragma unroll
    for (int kk = 0; kk < 2; ++kk) {
      short8 ap = *(const short8*)&pS[(wv * 16 + l15) * SP + kk * 32 + lk];
#pragma unroll
      for (int nt = 0; nt < 2; ++nt) {
        short8 bv = *(const short8*)&vS[(h * 32 + nt * 16 + l15) * SV + kk * 32 + lk];
        oa[nt] = __builtin_amdgcn_mfma_f32_16x16x32_bf16(ap, bv, oa[nt], 0, 0, 0);
      }
    }
    // O = PV + LePE (read parked LePE from hA, overwrite in place)
#pragma unroll
    for (int nt = 0; nt < 2; ++nt) {
      int c = h * 32 + nt * 16 + l15;
#pragma unroll
      for (int r = 0; r < 4; ++r) {
        int tk = wv * 16 + lr + r;
        hA[tk * SA + c] = f2b(oa[nt][r] + b2f(hA[tk * SA + c]));
      }
    }
  }
  // NO barrier: proj reads only this wave's own hA rows (all written above).

  // ---- proj + residual epilogue ----
  {
    f32x4 pacc[6];
#pragma unroll
    for (int t = 0; t < 6; ++t) pacc[t] = (f32x4){0.f, 0.f, 0.f, 0.f};
    __builtin_amdgcn_s_setprio(1);
#pragma unroll
    for (int kk = 0; kk < 3; ++kk) {
      short8 ao = *(const short8*)&hA[(wv * 16 + l15) * SA + kk * 32 + lk];
#pragma unroll
      for (int nt = 0; nt < 6; ++nt) {
        short8 bw = *(const short8*)&ws[O_WPROJT + (nt * 16 + l15) * 96 + kk * 32 + lk];
        pacc[nt] = __builtin_amdgcn_mfma_f32_16x16x32_bf16(ao, bw, pacc[nt], 0, 0, 0);
      }
    }
    __builtin_amdgcn_s_setprio(0);
#pragma unroll
    for (int nt = 0; nt < 6; ++nt) {
      int ch = nt * 16 + l15;
      float bias = bproj[ch];
#pragma unroll
      for (int r = 0; r < 4; ++r) {
        int tk = wv * 16 + lr + r;
        long g = xbase + (long)((wr * 8 + (tk >> 3)) * RDIM + wc * 8 + (tk & 7)) * CDIM + ch;
        out[g] = x[g] + pacc[nt][r] + bias;
      }
    }
  }
}

// =====================================================================
// Kernel B (MFMA): 64 tokens per block, 4 waves, wave-private everything.
// THIS ROUND: __launch_bounds__(256) with NO min-waves arg. Round 5's
// (256,6) forced VGPR 60->40 and spilled (+180 MB scratch HBM traffic,
// 127->190 us). Non-coercive hint: compiler keeps natural ~60 VGPR
// (zero spill), occupancy bounded by LDS (26624 -> 6 blocks/CU) and
// actual VGPR at dispatch. Worst case = current 4 blocks; likely 5-6.
// =====================================================================
__global__ __launch_bounds__(256)
void mlp_mfma(const float* __restrict__ bfc1, const float* __restrict__ bfc2,
              const float* __restrict__ g2, const float* __restrict__ bt2,
              const unsigned short* __restrict__ ws, float* __restrict__ out) {
  constexpr int SB = 104;
  constexpr int SHQ = 104;
  __shared__ __attribute__((aligned(16))) unsigned short hB[64 * SB];
  __shared__ __attribute__((aligned(16))) unsigned short Hq[64 * SHQ];

  const int tid = threadIdx.x, lane = tid & 63;
  const int wv = __builtin_amdgcn_readfirstlane(tid >> 6);
  const long t0 = (long)blockIdx.x * GG;
  const int l15 = lane & 15, lk = (lane >> 4) * 8, lr = (lane >> 4) * 4;
  const int p = lane >> 4;
  const int tok = wv * 16 + l15;

  {
    const float* rb = out + (t0 + tok) * CDIM + p * 24;
    float xv[24], s1 = 0.f, s2 = 0.f;
#pragma unroll
    for (int i = 0; i < 6; ++i) {
      f32x4 v4 = *(const f32x4*)(rb + i * 4);
#pragma unroll
      for (int j = 0; j < 4; ++j) {
        float v = v4[j];
        xv[i * 4 + j] = v; s1 += v; s2 += v * v;
      }
    }
    s1 += __shfl_xor(s1, 16, 64); s1 += __shfl_xor(s1, 32, 64);
    s2 += __shfl_xor(s2, 16, 64); s2 += __shfl_xor(s2, 32, 64);
    float m = s1 * (1.f / 96.f);
    float vv = s2 * (1.f / 96.f) - m * m;
    float rs = rsqrtf(vv + 1e-5f);
    unsigned short tmp[24];
#pragma unroll
    for (int i = 0; i < 24; ++i) {
      int c = p * 24 + i;
      tmp[i] = f2b((xv[i] - m) * rs * g2[c] + bt2[c]);
    }
#pragma unroll
    for (int i = 0; i < 3; ++i)
      *(short8*)&hB[tok * SB + p * 24 + i * 8] = *(const short8*)&tmp[i * 8];
  }

  f32x4 acc2[6];
#pragma unroll
  for (int t = 0; t < 6; ++t) acc2[t] = (f32x4){0.f, 0.f, 0.f, 0.f};

#pragma unroll 1
  for (int q = 0; q < 4; ++q) {
    f32x4 acc1[6];
#pragma unroll
    for (int t = 0; t < 6; ++t) acc1[t] = (f32x4){0.f, 0.f, 0.f, 0.f};
#pragma unroll
    for (int kk = 0; kk < 3; ++kk) {
      short8 a = *(const short8*)&hB[(wv * 16 + l15) * SB + kk * 32 + lk];
#pragma unroll
      for (int nt = 0; nt < 6; ++nt) {
        int n = q * 96 + nt * 16 + l15;
        short8 bw = *(const short8*)&ws[O_WFC1T + n * 96 + kk * 32 + lk];
        acc1[nt] = __builtin_amdgcn_mfma_f32_16x16x32_bf16(a, bw, acc1[nt], 0, 0, 0);
      }
    }
#pragma unroll
    for (int nt = 0; nt < 6; ++nt) {
      int n = q * 96 + nt * 16 + l15;
      float bias = bfc1[n];
#pragma unroll
      for (int r = 0; r < 4; ++r) {
        int tk = wv * 16 + lr + r;
        Hq[tk * SHQ + nt * 16 + l15] = f2b(gelu_f(acc1[nt][r] + bias));
      }
    }
#pragma unroll
    for (int kk = 0; kk < 3; ++kk) {
      short8 a = *(const short8*)&Hq[(wv * 16 + l15) * SHQ + kk * 32 + lk];
#pragma unroll
      for (int nt = 0; nt < 6; ++nt) {
        short8 bw = *(const short8*)&ws[O_WFC2T + (nt * 16 + l15) * 384 + q * 96 + kk * 32 + lk];
        acc2[nt] = __builtin_amdgcn_mfma_f32_16x16x32_bf16(a, bw, acc2[nt], 0, 0, 0);
      }
    }
  }

#pragma unroll
  for (int nt = 0; nt < 6; ++nt) {
    int ch = nt * 16 + l15;
    float bias = bfc2[ch];
#pragma unroll
    for (int r = 0; r < 4; ++r) {
      int tk = wv * 16 + lr + r;
      long g = (t0 + tk) * CDIM + ch;
      out[g] = out[g] + acc2[nt][r] + bias;
    }
  }
}

// =====================================================================
// Scalar fallback (round-2 proven path), used only if ws too small.
// =====================================================================
struct PF {
  const float *x, *w_qkv, *b_qkv, *w_lepe, *b_lepe, *w_proj, *b_proj;
  const float *g1, *bt1, *g2, *bt2, *w_fc1, *b_fc1, *w_fc2, *b_fc2;
  float* out;
};

__global__ __launch_bounds__(256, 2)
void attn_scalar(PF p) {
  constexpr int SA = 66;
  __shared__ __hip_bfloat16 bufA[CDIM * SA];
  __shared__ __hip_bfloat16 qkvT[288 * GG];
  __shared__ __hip_bfloat16 sPad[GG * SA];
  __shared__ float meanS[GG], rstdS[GG];

  const int w = blockIdx.x;
  const int b = w >> 6, wi = w & 63, wr = wi >> 3, wc = wi & 7;
  const int tid = threadIdx.x, lane = tid & 63;
  const int wv = __builtin_amdgcn_readfirstlane(tid >> 6);
  const long xbase = (long)b * (LTOK * CDIM);

  for (int k = 0; k < 24; ++k) {
    int e = tid + k * 256, wrow = e / 768, o = e - wrow * 768;
    int tir = o / 96, ch = o - tir * 96;
    long g = xbase + ((wr * 8 + wrow) * RDIM + wc * 8 + tir) * CDIM + ch;
    bufA[ch * SA + wrow * 8 + tir] = __float2bfloat16(p.x[g]);
  }
  __syncthreads();
  if (wv == 0) {
    float m = 0.f;
    for (int c = 0; c < CDIM; ++c) m += __bfloat162float(bufA[c * SA + lane]);
    m *= (1.f / CDIM);
    float var = 0.f;
    for (int c = 0; c < CDIM; ++c) {
      float d = __bfloat162float(bufA[c * SA + lane]) - m;
      var += d * d;
    }
    meanS[lane] = m;
    rstdS[lane] = rsqrtf(var * (1.f / CDIM) + 1e-5f);
  }
  __syncthreads();
  {
    float m = meanS[lane], rs = rstdS[lane];
    for (int cc = 0; cc < 24; ++cc) {
      int c = wv * 24 + cc;
      float v = __bfloat162float(bufA[c * SA + lane]);
      bufA[c * SA + lane] = __float2bfloat16((v - m) * rs * p.g1[c] + p.bt1[c]);
    }
  }
  __syncthreads();
  for (int tile = 0; tile < 2; ++tile) {
    int j0 = wv * 72 + tile * 36;
    float acc[36];
#pragma unroll
    for (int jj = 0; jj < 36; ++jj) acc[jj] = p.b_qkv[j0 + jj];
#pragma unroll 1
    for (int c = 0; c < CDIM; ++c) {
      float hv = __bfloat162float(bufA[c * SA + lane]);
#pragma unroll
      for (int jj = 0; jj < 36; ++jj) acc[jj] += hv * p.w_qkv[c * 288 + j0 + jj];
    }
#pragma unroll
    for (int jj = 0; jj < 36; ++jj)
      qkvT[(j0 + jj) * GG + lane] = __float2bfloat16(acc[jj]);
  }
  __syncthreads();
  for (int hh = 0; hh < NH_; ++hh) {
    float kreg[HD_];
#pragma unroll
    for (int d = 0; d < HD_; ++d)
      kreg[d] = __bfloat162float(qkvT[(CDIM + hh * HD_ + d) * GG + lane]);
#pragma unroll 1
    for (int r = 0; r < 16; ++r) {
      int i = wv * 16 + r;
      float acc = 0.f;
#pragma unroll
      for (int d = 0; d < HD_; ++d)
        acc += __bfloat162float(qkvT[(hh * HD_ + d) * GG + i]) * kreg[d];
      sPad[lane * SA + i] = __float2bfloat16(acc * SCALE);
    }
#pragma unroll 1
    for (int r = 0; r < 16; ++r) {
      int i = wv * 16 + r;
      float v = __bfloat162float(sPad[lane * SA + i]);
      float mx = v;
#pragma unroll
      for (int s = 32; s > 0; s >>= 1) mx = fmaxf(mx, __shfl_xor(mx, s, 64));
      float e = __expf(v - mx);
      float sum = e;
#pragma unroll
      for (int s = 32; s > 0; s >>= 1) sum += __shfl_xor(sum, s, 64);
      float rr = e / sum;
      sPad[lane * SA + i] = __float2bfloat16(rr);
      p.out[OUT1OFF + ((long)(w * NH_ + hh) * GG + i) * GG + lane] = rr;
    }
    __syncthreads();
    {
      int d0 = wv * 8;
      float acc[8];
#pragma unroll
      for (int dd = 0; dd < 8; ++dd) acc[dd] = 0.f;
#pragma unroll 1
      for (int j = 0; j < GG; ++j) {
        float sv = __bfloat162float(sPad[j * SA + lane]);
#pragma unroll
        for (int dd = 0; dd < 8; ++dd)
          acc[dd] += sv * __bfloat162float(qkvT[(2 * CDIM + hh * HD_ + d0 + dd) * GG + j]);
      }
      int tr = lane >> 3, tc = lane & 7;
#pragma unroll
      for (int dd = 0; dd < 8; ++dd) {
        int c = hh * HD_ + d0 + dd;
        float a = p.b_lepe[c];
#pragma unroll
        for (int kh = 0; kh < 3; ++kh)
#pragma unroll
          for (int kw = 0; kw < 3; ++kw) {
            int rr2 = tr + kh - 1, cc2 = tc + kw - 1;
            if (rr2 >= 0 && rr2 < 8 && cc2 >= 0 && cc2 < 8)
              a += p.w_lepe[c * 9 + kh * 3 + kw] *
                   __bfloat162float(qkvT[(2 * CDIM + hh * HD_ + d0 + dd) * GG + rr2 * 8 + cc2]);
          }
        acc[dd] += a;
      }
#pragma unroll
      for (int dd = 0; dd < 8; ++dd)
        bufA[(hh * HD_ + d0 + dd) * SA + lane] = __float2bfloat16(acc[dd]);
    }
    __syncthreads();
  }
  __hip_bfloat16* projT = qkvT;
  {
    int j0 = wv * 24;
    float acc[24];
#pragma unroll
    for (int jj = 0; jj < 24; ++jj) acc[jj] = p.b_proj[j0 + jj];
#pragma unroll 1
    for (int c = 0; c < CDIM; ++c) {
      float ov = __bfloat162float(bufA[c * SA + lane]);
#pragma unroll
      for (int jj = 0; jj < 24; ++jj) acc[jj] += ov * p.w_proj[c * CDIM + j0 + jj];
    }
#pragma unroll
    for (int jj = 0; jj < 24; ++jj)
      projT[(j0 + jj) * SA + lane] = __float2bfloat16(acc[jj]);
  }
  __syncthreads();
  for (int k = 0; k < 24; ++k) {
    int e = tid + k * 256, wrow = e / 768, o = e - wrow * 768;
    int tir = o / 96, ch = o - tir * 96;
    long g = xbase + ((wr * 8 + wrow) * RDIM + wc * 8 + tir) * CDIM + ch;
    p.out[g] = p.x[g] + __bfloat162float(projT[ch * SA + wrow * 8 + tir]);
  }
}

__global__ __launch_bounds__(256, 2)
void mlp_scalar(PF p) {
  constexpr int SB = 66;
  __shared__ __hip_bfloat16 bufB[CDIM * SB];
  __shared__ __hip_bfloat16 hidT[HID * GG];
  __shared__ float meanS[GG], rstdS[GG];

  const int tid = threadIdx.x, lane = tid & 63;
  const int wv = __builtin_amdgcn_readfirstlane(tid >> 6);
  const long t0 = (long)blockIdx.x * GG;

  for (int k = 0; k < 24; ++k) {
    int e = tid + k * 256, tok = e / 96, ch = e - tok * 96;
    bufB[ch * SB + tok] = __float2bfloat16(p.out[(t0 + tok) * CDIM + ch]);
  }
  __syncthreads();
  if (wv == 0) {
    float m = 0.f;
    for (int c = 0; c < CDIM; ++c) m += __bfloat162float(bufB[c * SB + lane]);
    m *= (1.f / CDIM);
    float var = 0.f;
    for (int c = 0; c < CDIM; ++c) {
      float d = __bfloat162float(bufB[c * SB + lane]) - m;
      var += d * d;
    }
    meanS[lane] = m;
    rstdS[lane] = rsqrtf(var * (1.f / CDIM) + 1e-5f);
  }
  __syncthreads();
  {
    float m = meanS[lane], rs = rstdS[lane];
    for (int cc = 0; cc < 24; ++cc) {
      int c = wv * 24 + cc;
      float v = __bfloat162float(bufB[c * SB + lane]);
      bufB[c * SB + lane] = __float2bfloat16((v - m) * rs * p.g2[c] + p.bt2[c]);
    }
  }
  __syncthreads();
  for (int tile = 0; tile < 4; ++tile) {
    int j0 = wv * 96 + tile * 24;
    float acc[24];
#pragma unroll
    for (int jj = 0; jj < 24; ++jj) acc[jj] = p.b_fc1[j0 + jj];
#pragma unroll 1
    for (int c = 0; c < CDIM; ++c) {
      float hv = __bfloat162float(bufB[c * SB + lane]);
#pragma unroll
      for (int jj = 0; jj < 24; ++jj) acc[jj] += hv * p.w_fc1[c * HID + j0 + jj];
    }
#pragma unroll
    for (int jj = 0; jj < 24; ++jj) {
      float xg = acc[jj];
      hidT[(j0 + jj) * GG + lane] =
          __float2bfloat16(0.5f * xg * (1.f + erff(xg * 0.70710678118f)));
    }
  }
  __syncthreads();
  {
    int j0 = wv * 24;
    float acc[24];
#pragma unroll
    for (int jj = 0; jj < 24; ++jj) acc[jj] = p.b_fc2[j0 + jj];
#pragma unroll 1
    for (int h = 0; h < HID; ++h) {
      float hv = __bfloat162float(hidT[h * GG + lane]);
#pragma unroll
      for (int jj = 0; jj < 24; ++jj) acc[jj] += hv * p.w_fc2[h * CDIM + j0 + jj];
    }
#pragma unroll
    for (int jj = 0; jj < 24; ++jj)
      bufB[(j0 + jj) * SB + lane] = __float2bfloat16(acc[jj]);
  }
  __syncthreads();
  for (int k = 0; k < 24; ++k) {
    int e = tid + k * 256, tok = e / 96, ch = e - tok * 96;
    long g = (t0 + tok) * CDIM + ch;
    p.out[g] = p.out[g] + __bfloat162float(bufB[ch * SB + tok]);
  }
}

extern "C" void kernel_launch(void* const* d_in, const int* in_sizes, int n_in,
                              void* d_out, int out_size, void* d_ws, size_t ws_size,
                              hipStream_t stream) {
  const float* x = (const float*)d_in[0];
  const float* w_qkv = (const float*)d_in[1];
  const float* b_qkv = (const float*)d_in[2];
  const float* w_lepe = (const float*)d_in[3];
  const float* b_lepe = (const float*)d_in[4];
  const float* w_proj = (const float*)d_in[5];
  const float* b_proj = (const float*)d_in[6];
  const float* g1 = (const float*)d_in[7];
  const float* bt1 = (const float*)d_in[8];
  const float* g2 = (const float*)d_in[9];
  const float* bt2 = (const float*)d_in[10];
  const float* w_fc1 = (const float*)d_in[11];
  const float* b_fc1 = (const float*)d_in[12];
  const float* w_fc2 = (const float*)d_in[13];
  const float* b_fc2 = (const float*)d_in[14];
  float* out = (float*)d_out;
  const int mlp_blocks = (BDIM * LTOK) / GG;  // 2048

  if (ws_size >= (size_t)W_TOT * sizeof(unsigned short)) {
    unsigned short* ws = (unsigned short*)d_ws;
    prep_weights<<<(W_TOT + 255) / 256, 256, 0, stream>>>(w_qkv, w_proj, w_fc1, w_fc2, ws);
    attn_mfma<<<NWIN, 256, 0, stream>>>(x, b_qkv, w_lepe, b_lepe, b_proj, g1, bt1, ws, out);
    mlp_mfma<<<mlp_blocks, 256, 0, stream>>>(b_fc1, b_fc2, g2, bt2, ws, out);
  } else {
    PF p{x, w_qkv, b_qkv, w_lepe, b_lepe, w_proj, b_proj,
         g1, bt1, g2, bt2, w_fc1, b_fc1, w_fc2, b_fc2, out};
    attn_scalar<<<NWIN, 256, 0, stream>>>(p);
    mlp_scalar<<<mlp_blocks, 256, 0, stream>>>(p);
  }
}

// Round 7
// 348.788 us; speedup vs baseline: 1.2474x; 1.1175x over previous
//
#include <hip/hip_runtime.h>
#include <hip/hip_bf16.h>

typedef short short8 __attribute__((ext_vector_type(8)));
typedef float f32x4 __attribute__((ext_vector_type(4)));

constexpr int BDIM = 32, RDIM = 64, CDIM = 96, NH_ = 3, HD_ = 32;
constexpr int LTOK = RDIM * RDIM;      // 4096
constexpr int GG = 64;
constexpr int HID = 384;
constexpr int NWIN = 2048;
constexpr float SCALE = 0.17677669529663687f;
constexpr long OUT1OFF = (long)BDIM * LTOK * CDIM;   // 12582912

// ws layout (bf16 element offsets): transposed weights [n][k], k-contiguous
constexpr int O_WQKVT = 0;        // [288][96]
constexpr int O_WPROJT = 27648;   // [96][96]
constexpr int O_WFC1T = 36864;    // [384][96]
constexpr int O_WFC2T = 73728;    // [96][384]
constexpr int W_TOT = 110592;

__device__ __forceinline__ unsigned short f2b(float f) {
  return __builtin_bit_cast(unsigned short, __float2bfloat16(f));
}
__device__ __forceinline__ float b2f(unsigned short u) {
  return __bfloat162float(__builtin_bit_cast(__hip_bfloat16, u));
}

// Exact-GELU via Abramowitz-Stegun 7.1.26 erf (|eps| <= 1.5e-7).
__device__ __forceinline__ float gelu_f(float x) {
  float u = x * 0.70710678118654752f;
  float ax = __builtin_fabsf(u);
  float t = __builtin_amdgcn_rcpf(1.f + 0.3275911f * ax);
  float poly = t * (0.254829592f +
               t * (-0.284496736f +
               t * (1.421413741f +
               t * (-1.453152027f +
               t * 1.061405429f))));
  float erf_abs = 1.f - poly * __expf(-ax * ax);
  float erf_u = (u < 0.f) ? -erf_abs : erf_abs;
  return 0.5f * x * (1.f + erf_u);
}

// ---------------- weight transpose+cvt prep ----------------
__global__ void prep_weights(const float* __restrict__ wqkv,
                             const float* __restrict__ wproj,
                             const float* __restrict__ wfc1,
                             const float* __restrict__ wfc2,
                             unsigned short* __restrict__ ws) {
  int i = blockIdx.x * 256 + threadIdx.x;
  if (i >= W_TOT) return;
  float v;
  if (i < O_WPROJT) {
    int n = i / 96, k = i - n * 96;
    v = wqkv[k * 288 + n];
  } else if (i < O_WFC1T) {
    int j = i - O_WPROJT, n = j / 96, k = j - n * 96;
    v = wproj[k * 96 + n];
  } else if (i < O_WFC2T) {
    int j = i - O_WFC1T, n = j / 96, k = j - n * 96;
    v = wfc1[k * 384 + n];
  } else {
    int j = i - O_WFC2T, n = j / 384, k = j - n * 384;
    v = wfc2[k * 96 + n];
  }
  ws[i] = f2b(v);
}

// =====================================================================
// FUSED kernel: one 8x8 window (64 tokens) per block, 4 waves.
// attn part = round-2 proven code, byte-identical through proj MFMA.
// Then (all wave-private, zero new barriers):
//   x1 = x + proj + bias kept in regs (never hits HBM),
//   LN2 in-register (16-lane shfl butterfly), h2 -> hA own rows,
//   fc1+GELU+fc2 quarter-loop (round-2 proven mlp body, hA input,
//   fresh Hq buffer -- no aliasing), out = x1 + fc2 + bias (one store).
// LDS 75264 B x 2 blocks = 150528 <= 163840 -> 2 blocks/CU.
// =====================================================================
__global__ __launch_bounds__(256, 2)
void attn_mlp_mfma(const float* __restrict__ x, const float* __restrict__ bqkv,
                   const float* __restrict__ wlepe, const float* __restrict__ blepe,
                   const float* __restrict__ bproj, const float* __restrict__ g1,
                   const float* __restrict__ bt1, const float* __restrict__ g2,
                   const float* __restrict__ bt2, const float* __restrict__ bfc1,
                   const float* __restrict__ bfc2,
                   const unsigned short* __restrict__ ws, float* __restrict__ out) {
  constexpr int SA = 104;   // hA stride: h, LePE, O, then h2 (mlp input)
  constexpr int SQ = 200;   // qkS stride (q cols 0..95, k cols 96..191)
  constexpr int SV = 72;    // vS stride
  constexpr int SP = 72;    // pS stride
  constexpr int SHQ = 104;  // Hq stride (mlp hidden quarter)
  __shared__ __attribute__((aligned(16))) unsigned short hA[64 * SA];
  __shared__ __attribute__((aligned(16))) unsigned short qkS[64 * SQ];
  __shared__ __attribute__((aligned(16))) unsigned short vS[96 * SV];
  __shared__ __attribute__((aligned(16))) unsigned short pS[64 * SP];
  __shared__ __attribute__((aligned(16))) unsigned short Hq[64 * SHQ];

  const int tid = threadIdx.x, lane = tid & 63;
  const int wv = __builtin_amdgcn_readfirstlane(tid >> 6);
  const int w = blockIdx.x, b = w >> 6, wi = w & 63, wr = wi >> 3, wc = wi & 7;
  const long xbase = (long)b * (LTOK * CDIM);
  const int l15 = lane & 15, lk = (lane >> 4) * 8, lr = (lane >> 4) * 4;
  const int p = lane >> 4;            // channel quarter for LN phase
  const int tok = wv * 16 + l15;      // wave-private token for LN phase

  // ---- load + LN1 (wave-private tokens; shfl reduce; no barrier) ----
  {
    const long rowbase =
        xbase + (long)((wr * 8 + (tok >> 3)) * RDIM + wc * 8 + (tok & 7)) * CDIM;
    const float* rb = x + rowbase + p * 24;
    float xv[24], s1 = 0.f, s2 = 0.f;
#pragma unroll
    for (int i = 0; i < 6; ++i) {
      f32x4 v4 = *(const f32x4*)(rb + i * 4);
#pragma unroll
      for (int j = 0; j < 4; ++j) {
        float v = v4[j];
        xv[i * 4 + j] = v; s1 += v; s2 += v * v;
      }
    }
    s1 += __shfl_xor(s1, 16, 64); s1 += __shfl_xor(s1, 32, 64);
    s2 += __shfl_xor(s2, 16, 64); s2 += __shfl_xor(s2, 32, 64);
    float m = s1 * (1.f / 96.f);
    float vv = s2 * (1.f / 96.f) - m * m;
    float rs = rsqrtf(vv + 1e-5f);
    unsigned short tmp[24];
#pragma unroll
    for (int i = 0; i < 6; ++i) {
      f32x4 gv = *(const f32x4*)(g1 + p * 24 + i * 4);
      f32x4 bv = *(const f32x4*)(bt1 + p * 24 + i * 4);
#pragma unroll
      for (int j = 0; j < 4; ++j)
        tmp[i * 4 + j] = f2b((xv[i * 4 + j] - m) * rs * gv[j] + bv[j]);
    }
#pragma unroll
    for (int i = 0; i < 3; ++i)
      *(short8*)&hA[tok * SA + p * 24 + i * 8] = *(const short8*)&tmp[i * 8];
  }
  // NO barrier: qkv below reads only this wave's own hA rows.

  // ---- qkv: wave's 16 rows x 288 cols ----
  {
    f32x4 acc[18];
#pragma unroll
    for (int t = 0; t < 18; ++t) acc[t] = (f32x4){0.f, 0.f, 0.f, 0.f};
    const int arow = wv * 16 + l15;
    __builtin_amdgcn_s_setprio(1);
#pragma unroll
    for (int kk = 0; kk < 3; ++kk) {
      short8 a = *(const short8*)&hA[arow * SA + kk * 32 + lk];
#pragma unroll
      for (int nt = 0; nt < 18; ++nt) {
        short8 bw = *(const short8*)&ws[O_WQKVT + (nt * 16 + l15) * 96 + kk * 32 + lk];
        acc[nt] = __builtin_amdgcn_mfma_f32_16x16x32_bf16(a, bw, acc[nt], 0, 0, 0);
      }
    }
    __builtin_amdgcn_s_setprio(0);
    // stage q (scaled), k, v with bias
#pragma unroll
    for (int nt = 0; nt < 18; ++nt) {
      int n0 = nt * 16 + l15;
      float bias = bqkv[n0];
#pragma unroll
      for (int r = 0; r < 4; ++r) {
        int tk = wv * 16 + lr + r;
        float v = acc[nt][r] + bias;
        if (n0 < 96) qkS[tk * SQ + n0] = f2b(v * SCALE);
        else if (n0 < 192) qkS[tk * SQ + n0] = f2b(v);
        else vS[(n0 - 192) * SV + tk] = f2b(v);
      }
    }
  }
  __syncthreads();   // barrier A: k/v staged by all waves

  // ---- LePE pass: thread = (channel, 4-spatial-row strip) ----
  if (tid < 192) {
    const int c = tid >> 1;       // 0..95
    const int half = tid & 1;     // rows 0-3 / 4-7
    const int r0 = half * 4;
    float rowb[6][8];
#pragma unroll
    for (int rr = 0; rr < 6; ++rr) {
      int vr = r0 - 1 + rr;
      if (vr >= 0 && vr < 8) {
        short8 v8 = *(const short8*)&vS[c * SV + vr * 8];
#pragma unroll
        for (int j = 0; j < 8; ++j) rowb[rr][j] = b2f((unsigned short)v8[j]);
      } else {
#pragma unroll
        for (int j = 0; j < 8; ++j) rowb[rr][j] = 0.f;
      }
    }
    float lw9[9];
#pragma unroll
    for (int q = 0; q < 9; ++q) lw9[q] = wlepe[c * 9 + q];
    const float lb = blepe[c];
#pragma unroll
    for (int r = 0; r < 4; ++r) {
#pragma unroll
      for (int cc = 0; cc < 8; ++cc) {
        float a = lb;
#pragma unroll
        for (int kh = 0; kh < 3; ++kh) {
          const float* rbp = rowb[r + kh];
          if (cc > 0) a += lw9[kh * 3 + 0] * rbp[cc - 1];
          a += lw9[kh * 3 + 1] * rbp[cc];
          if (cc < 7) a += lw9[kh * 3 + 2] * rbp[cc + 1];
        }
        hA[((r0 + r) * 8 + cc) * SA + c] = f2b(a);
      }
    }
  }
  __syncthreads();   // barrier B: LePE parked in hA

  // ---- per-head attention ----
  for (int h = 0; h < NH_; ++h) {
    f32x4 sacc[4];
#pragma unroll
    for (int t = 0; t < 4; ++t) sacc[t] = (f32x4){0.f, 0.f, 0.f, 0.f};
    short8 aq = *(const short8*)&qkS[(wv * 16 + l15) * SQ + h * 32 + lk];
#pragma unroll
    for (int nt = 0; nt < 4; ++nt) {
      short8 bk = *(const short8*)&qkS[(nt * 16 + l15) * SQ + 96 + h * 32 + lk];
      sacc[nt] = __builtin_amdgcn_mfma_f32_16x16x32_bf16(aq, bk, sacc[nt], 0, 0, 0);
    }
    // softmax (rows live in 16-lane groups)
    float pr[4][4];
#pragma unroll
    for (int r = 0; r < 4; ++r) {
      float mx = -1e30f;
#pragma unroll
      for (int nt = 0; nt < 4; ++nt) mx = fmaxf(mx, sacc[nt][r]);
#pragma unroll
      for (int s = 1; s < 16; s <<= 1) mx = fmaxf(mx, __shfl_xor(mx, s, 64));
      float sum = 0.f;
#pragma unroll
      for (int nt = 0; nt < 4; ++nt) {
        float e = __expf(sacc[nt][r] - mx);
        pr[nt][r] = e; sum += e;
      }
#pragma unroll
      for (int s = 1; s < 16; s <<= 1) sum += __shfl_xor(sum, s, 64);
      float inv = 1.f / sum;
#pragma unroll
      for (int nt = 0; nt < 4; ++nt) pr[nt][r] *= inv;
    }
    // write attn probs (fp32) + stage P (bf16, wave-local rows)
    const long o1base = OUT1OFF + ((long)(w * NH_ + h) * GG) * GG;
#pragma unroll
    for (int nt = 0; nt < 4; ++nt) {
      int col = nt * 16 + l15;
#pragma unroll
      for (int r = 0; r < 4; ++r) {
        int row = wv * 16 + lr + r;
        out[o1base + (long)row * GG + col] = pr[nt][r];
        pS[row * SP + col] = f2b(pr[nt][r]);
      }
    }
    // PV (same wave produced pS rows; vS covered by barrier A)
    f32x4 oa[2];
    oa[0] = (f32x4){0.f, 0.f, 0.f, 0.f};
    oa[1] = (f32x4){0.f, 0.f, 0.f, 0.f};
#pragma unroll
    for (int kk = 0; kk < 2; ++kk) {
      short8 ap = *(const short8*)&pS[(wv * 16 + l15) * SP + kk * 32 + lk];
#pragma unroll
      for (int nt = 0; nt < 2; ++nt) {
        short8 bv = *(const short8*)&vS[(h * 32 + nt * 16 + l15) * SV + kk * 32 + lk];
        oa[nt] = __builtin_amdgcn_mfma_f32_16x16x32_bf16(ap, bv, oa[nt], 0, 0, 0);
      }
    }
    // O = PV + LePE (read parked LePE from hA, overwrite in place)
#pragma unroll
    for (int nt = 0; nt < 2; ++nt) {
      int c = h * 32 + nt * 16 + l15;
#pragma unroll
      for (int r = 0; r < 4; ++r) {
        int tk = wv * 16 + lr + r;
        hA[tk * SA + c] = f2b(oa[nt][r] + b2f(hA[tk * SA + c]));
      }
    }
  }
  // NO barrier: proj reads only this wave's own hA rows (all written above).

  // ---- proj MFMA ----
  f32x4 pacc[6];   // proj out, then x1 (held through the mlp tail)
#pragma unroll
  for (int t = 0; t < 6; ++t) pacc[t] = (f32x4){0.f, 0.f, 0.f, 0.f};
  {
    __builtin_amdgcn_s_setprio(1);
#pragma unroll
    for (int kk = 0; kk < 3; ++kk) {
      short8 ao = *(const short8*)&hA[(wv * 16 + l15) * SA + kk * 32 + lk];
#pragma unroll
      for (int nt = 0; nt < 6; ++nt) {
        short8 bw = *(const short8*)&ws[O_WPROJT + (nt * 16 + l15) * 96 + kk * 32 + lk];
        pacc[nt] = __builtin_amdgcn_mfma_f32_16x16x32_bf16(ao, bw, pacc[nt], 0, 0, 0);
      }
    }
    __builtin_amdgcn_s_setprio(0);
  }

  // ---- x1 = x + proj + bias (registers only; x1 never hits HBM) ----
  long grow[4];
#pragma unroll
  for (int r = 0; r < 4; ++r) {
    int tk = wv * 16 + lr + r;
    grow[r] = xbase + (long)((wr * 8 + (tk >> 3)) * RDIM + wc * 8 + (tk & 7)) * CDIM;
  }
#pragma unroll
  for (int nt = 0; nt < 6; ++nt) {
    int ch = nt * 16 + l15;
    float bias = bproj[ch];
#pragma unroll
    for (int r = 0; r < 4; ++r)
      pacc[nt][r] = x[grow[r] + ch] + pacc[nt][r] + bias;
  }

  // ---- LN2 in-register: per-token reduce across the 16 channel-lanes ----
  float m4[4], rs4[4];
#pragma unroll
  for (int r = 0; r < 4; ++r) {
    float s1 = 0.f, s2 = 0.f;
#pragma unroll
    for (int nt = 0; nt < 6; ++nt) { float v = pacc[nt][r]; s1 += v; s2 += v * v; }
#pragma unroll
    for (int s = 1; s < 16; s <<= 1) {
      s1 += __shfl_xor(s1, s, 64);
      s2 += __shfl_xor(s2, s, 64);
    }
    float m = s1 * (1.f / 96.f);
    float vv = s2 * (1.f / 96.f) - m * m;
    m4[r] = m; rs4[r] = rsqrtf(vv + 1e-5f);
  }
  // h2 -> hA own-wave rows (proven wave-private LDS write->read idiom)
#pragma unroll
  for (int nt = 0; nt < 6; ++nt) {
    int ch = nt * 16 + l15;
    float gg = g2[ch], bb = bt2[ch];
#pragma unroll
    for (int r = 0; r < 4; ++r) {
      int tk = wv * 16 + lr + r;
      hA[tk * SA + ch] = f2b((pacc[nt][r] - m4[r]) * rs4[r] * gg + bb);
    }
  }
  // NO barrier: fc1 below reads only this wave's own hA rows.

  // ---- MLP: 4x interleaved quarters of {fc1 -> GELU -> fc2 k-slice} ----
  f32x4 acc2[6];
#pragma unroll
  for (int t = 0; t < 6; ++t) acc2[t] = (f32x4){0.f, 0.f, 0.f, 0.f};

#pragma unroll 1
  for (int q = 0; q < 4; ++q) {
    f32x4 acc1[6];
#pragma unroll
    for (int t = 0; t < 6; ++t) acc1[t] = (f32x4){0.f, 0.f, 0.f, 0.f};
#pragma unroll
    for (int kk = 0; kk < 3; ++kk) {
      short8 a = *(const short8*)&hA[(wv * 16 + l15) * SA + kk * 32 + lk];
#pragma unroll
      for (int nt = 0; nt < 6; ++nt) {
        int n = q * 96 + nt * 16 + l15;
        short8 bw = *(const short8*)&ws[O_WFC1T + n * 96 + kk * 32 + lk];
        acc1[nt] = __builtin_amdgcn_mfma_f32_16x16x32_bf16(a, bw, acc1[nt], 0, 0, 0);
      }
    }
#pragma unroll
    for (int nt = 0; nt < 6; ++nt) {
      int n = q * 96 + nt * 16 + l15;
      float bias = bfc1[n];
#pragma unroll
      for (int r = 0; r < 4; ++r) {
        int tk = wv * 16 + lr + r;
        Hq[tk * SHQ + nt * 16 + l15] = f2b(gelu_f(acc1[nt][r] + bias));
      }
    }
#pragma unroll
    for (int kk = 0; kk < 3; ++kk) {
      short8 a = *(const short8*)&Hq[(wv * 16 + l15) * SHQ + kk * 32 + lk];
#pragma unroll
      for (int nt = 0; nt < 6; ++nt) {
        short8 bw = *(const short8*)&ws[O_WFC2T + (nt * 16 + l15) * 384 + q * 96 + kk * 32 + lk];
        acc2[nt] = __builtin_amdgcn_mfma_f32_16x16x32_bf16(a, bw, acc2[nt], 0, 0, 0);
      }
    }
  }

  // ---- single final store: out = x1 + fc2 + bias ----
#pragma unroll
  for (int nt = 0; nt < 6; ++nt) {
    int ch = nt * 16 + l15;
    float bias = bfc2[ch];
#pragma unroll
    for (int r = 0; r < 4; ++r)
      out[grow[r] + ch] = pacc[nt][r] + acc2[nt][r] + bias;
  }
}

// =====================================================================
// Scalar fallback (round-2 proven path), used only if ws too small.
// =====================================================================
struct PF {
  const float *x, *w_qkv, *b_qkv, *w_lepe, *b_lepe, *w_proj, *b_proj;
  const float *g1, *bt1, *g2, *bt2, *w_fc1, *b_fc1, *w_fc2, *b_fc2;
  float* out;
};

__global__ __launch_bounds__(256, 2)
void attn_scalar(PF p) {
  constexpr int SA = 66;
  __shared__ __hip_bfloat16 bufA[CDIM * SA];
  __shared__ __hip_bfloat16 qkvT[288 * GG];
  __shared__ __hip_bfloat16 sPad[GG * SA];
  __shared__ float meanS[GG], rstdS[GG];

  const int w = blockIdx.x;
  const int b = w >> 6, wi = w & 63, wr = wi >> 3, wc = wi & 7;
  const int tid = threadIdx.x, lane = tid & 63;
  const int wv = __builtin_amdgcn_readfirstlane(tid >> 6);
  const long xbase = (long)b * (LTOK * CDIM);

  for (int k = 0; k < 24; ++k) {
    int e = tid + k * 256, wrow = e / 768, o = e - wrow * 768;
    int tir = o / 96, ch = o - tir * 96;
    long g = xbase + ((wr * 8 + wrow) * RDIM + wc * 8 + tir) * CDIM + ch;
    bufA[ch * SA + wrow * 8 + tir] = __float2bfloat16(p.x[g]);
  }
  __syncthreads();
  if (wv == 0) {
    float m = 0.f;
    for (int c = 0; c < CDIM; ++c) m += __bfloat162float(bufA[c * SA + lane]);
    m *= (1.f / CDIM);
    float var = 0.f;
    for (int c = 0; c < CDIM; ++c) {
      float d = __bfloat162float(bufA[c * SA + lane]) - m;
      var += d * d;
    }
    meanS[lane] = m;
    rstdS[lane] = rsqrtf(var * (1.f / CDIM) + 1e-5f);
  }
  __syncthreads();
  {
    float m = meanS[lane], rs = rstdS[lane];
    for (int cc = 0; cc < 24; ++cc) {
      int c = wv * 24 + cc;
      float v = __bfloat162float(bufA[c * SA + lane]);
      bufA[c * SA + lane] = __float2bfloat16((v - m) * rs * p.g1[c] + p.bt1[c]);
    }
  }
  __syncthreads();
  for (int tile = 0; tile < 2; ++tile) {
    int j0 = wv * 72 + tile * 36;
    float acc[36];
#pragma unroll
    for (int jj = 0; jj < 36; ++jj) acc[jj] = p.b_qkv[j0 + jj];
#pragma unroll 1
    for (int c = 0; c < CDIM; ++c) {
      float hv = __bfloat162float(bufA[c * SA + lane]);
#pragma unroll
      for (int jj = 0; jj < 36; ++jj) acc[jj] += hv * p.w_qkv[c * 288 + j0 + jj];
    }
#pragma unroll
    for (int jj = 0; jj < 36; ++jj)
      qkvT[(j0 + jj) * GG + lane] = __float2bfloat16(acc[jj]);
  }
  __syncthreads();
  for (int hh = 0; hh < NH_; ++hh) {
    float kreg[HD_];
#pragma unroll
    for (int d = 0; d < HD_; ++d)
      kreg[d] = __bfloat162float(qkvT[(CDIM + hh * HD_ + d) * GG + lane]);
#pragma unroll 1
    for (int r = 0; r < 16; ++r) {
      int i = wv * 16 + r;
      float acc = 0.f;
#pragma unroll
      for (int d = 0; d < HD_; ++d)
        acc += __bfloat162float(qkvT[(hh * HD_ + d) * GG + i]) * kreg[d];
      sPad[lane * SA + i] = __float2bfloat16(acc * SCALE);
    }
#pragma unroll 1
    for (int r = 0; r < 16; ++r) {
      int i = wv * 16 + r;
      float v = __bfloat162float(sPad[lane * SA + i]);
      float mx = v;
#pragma unroll
      for (int s = 32; s > 0; s >>= 1) mx = fmaxf(mx, __shfl_xor(mx, s, 64));
      float e = __expf(v - mx);
      float sum = e;
#pragma unroll
      for (int s = 32; s > 0; s >>= 1) sum += __shfl_xor(sum, s, 64);
      float rr = e / sum;
      sPad[lane * SA + i] = __float2bfloat16(rr);
      p.out[OUT1OFF + ((long)(w * NH_ + hh) * GG + i) * GG + lane] = rr;
    }
    __syncthreads();
    {
      int d0 = wv * 8;
      float acc[8];
#pragma unroll
      for (int dd = 0; dd < 8; ++dd) acc[dd] = 0.f;
#pragma unroll 1
      for (int j = 0; j < GG; ++j) {
        float sv = __bfloat162float(sPad[j * SA + lane]);
#pragma unroll
        for (int dd = 0; dd < 8; ++dd)
          acc[dd] += sv * __bfloat162float(qkvT[(2 * CDIM + hh * HD_ + d0 + dd) * GG + j]);
      }
      int tr = lane >> 3, tc = lane & 7;
#pragma unroll
      for (int dd = 0; dd < 8; ++dd) {
        int c = hh * HD_ + d0 + dd;
        float a = p.b_lepe[c];
#pragma unroll
        for (int kh = 0; kh < 3; ++kh)
#pragma unroll
          for (int kw = 0; kw < 3; ++kw) {
            int rr2 = tr + kh - 1, cc2 = tc + kw - 1;
            if (rr2 >= 0 && rr2 < 8 && cc2 >= 0 && cc2 < 8)
              a += p.w_lepe[c * 9 + kh * 3 + kw] *
                   __bfloat162float(qkvT[(2 * CDIM + hh * HD_ + d0 + dd) * GG + rr2 * 8 + cc2]);
          }
        acc[dd] += a;
      }
#pragma unroll
      for (int dd = 0; dd < 8; ++dd)
        bufA[(hh * HD_ + d0 + dd) * SA + lane] = __float2bfloat16(acc[dd]);
    }
    __syncthreads();
  }
  __hip_bfloat16* projT = qkvT;
  {
    int j0 = wv * 24;
    float acc[24];
#pragma unroll
    for (int jj = 0; jj < 24; ++jj) acc[jj] = p.b_proj[j0 + jj];
#pragma unroll 1
    for (int c = 0; c < CDIM; ++c) {
      float ov = __bfloat162float(bufA[c * SA + lane]);
#pragma unroll
      for (int jj = 0; jj < 24; ++jj) acc[jj] += ov * p.w_proj[c * CDIM + j0 + jj];
    }
#pragma unroll
    for (int jj = 0; jj < 24; ++jj)
      projT[(j0 + jj) * SA + lane] = __float2bfloat16(acc[jj]);
  }
  __syncthreads();
  for (int k = 0; k < 24; ++k) {
    int e = tid + k * 256, wrow = e / 768, o = e - wrow * 768;
    int tir = o / 96, ch = o - tir * 96;
    long g = xbase + ((wr * 8 + wrow) * RDIM + wc * 8 + tir) * CDIM + ch;
    p.out[g] = p.x[g] + __bfloat162float(projT[ch * SA + wrow * 8 + tir]);
  }
}

__global__ __launch_bounds__(256, 2)
void mlp_scalar(PF p) {
  constexpr int SB = 66;
  __shared__ __hip_bfloat16 bufB[CDIM * SB];
  __shared__ __hip_bfloat16 hidT[HID * GG];
  __shared__ float meanS[GG], rstdS[GG];

  const int tid = threadIdx.x, lane = tid & 63;
  const int wv = __builtin_amdgcn_readfirstlane(tid >> 6);
  const long t0 = (long)blockIdx.x * GG;

  for (int k = 0; k < 24; ++k) {
    int e = tid + k * 256, tok = e / 96, ch = e - tok * 96;
    bufB[ch * SB + tok] = __float2bfloat16(p.out[(t0 + tok) * CDIM + ch]);
  }
  __syncthreads();
  if (wv == 0) {
    float m = 0.f;
    for (int c = 0; c < CDIM; ++c) m += __bfloat162float(bufB[c * SB + lane]);
    m *= (1.f / CDIM);
    float var = 0.f;
    for (int c = 0; c < CDIM; ++c) {
      float d = __bfloat162float(bufB[c * SB + lane]) - m;
      var += d * d;
    }
    meanS[lane] = m;
    rstdS[lane] = rsqrtf(var * (1.f / CDIM) + 1e-5f);
  }
  __syncthreads();
  {
    float m = meanS[lane], rs = rstdS[lane];
    for (int cc = 0; cc < 24; ++cc) {
      int c = wv * 24 + cc;
      float v = __bfloat162float(bufB[c * SB + lane]);
      bufB[c * SB + lane] = __float2bfloat16((v - m) * rs * p.g2[c] + p.bt2[c]);
    }
  }
  __syncthreads();
  for (int tile = 0; tile < 4; ++tile) {
    int j0 = wv * 96 + tile * 24;
    float acc[24];
#pragma unroll
    for (int jj = 0; jj < 24; ++jj) acc[jj] = p.b_fc1[j0 + jj];
#pragma unroll 1
    for (int c = 0; c < CDIM; ++c) {
      float hv = __bfloat162float(bufB[c * SB + lane]);
#pragma unroll
      for (int jj = 0; jj < 24; ++jj) acc[jj] += hv * p.w_fc1[c * HID + j0 + jj];
    }
#pragma unroll
    for (int jj = 0; jj < 24; ++jj) {
      float xg = acc[jj];
      hidT[(j0 + jj) * GG + lane] =
          __float2bfloat16(0.5f * xg * (1.f + erff(xg * 0.70710678118f)));
    }
  }
  __syncthreads();
  {
    int j0 = wv * 24;
    float acc[24];
#pragma unroll
    for (int jj = 0; jj < 24; ++jj) acc[jj] = p.b_fc2[j0 + jj];
#pragma unroll 1
    for (int h = 0; h < HID; ++h) {
      float hv = __bfloat162float(hidT[h * GG + lane]);
#pragma unroll
      for (int jj = 0; jj < 24; ++jj) acc[jj] += hv * p.w_fc2[h * CDIM + j0 + jj];
    }
#pragma unroll
    for (int jj = 0; jj < 24; ++jj)
      bufB[(j0 + jj) * SB + lane] = __float2bfloat16(acc[jj]);
  }
  __syncthreads();
  for (int k = 0; k < 24; ++k) {
    int e = tid + k * 256, tok = e / 96, ch = e - tok * 96;
    long g = (t0 + tok) * CDIM + ch;
    p.out[g] = p.out[g] + __bfloat162float(bufB[ch * SB + tok]);
  }
}

extern "C" void kernel_launch(void* const* d_in, const int* in_sizes, int n_in,
                              void* d_out, int out_size, void* d_ws, size_t ws_size,
                              hipStream_t stream) {
  const float* x = (const float*)d_in[0];
  const float* w_qkv = (const float*)d_in[1];
  const float* b_qkv = (const float*)d_in[2];
  const float* w_lepe = (const float*)d_in[3];
  const float* b_lepe = (const float*)d_in[4];
  const float* w_proj = (const float*)d_in[5];
  const float* b_proj = (const float*)d_in[6];
  const float* g1 = (const float*)d_in[7];
  const float* bt1 = (const float*)d_in[8];
  const float* g2 = (const float*)d_in[9];
  const float* bt2 = (const float*)d_in[10];
  const float* w_fc1 = (const float*)d_in[11];
  const float* b_fc1 = (const float*)d_in[12];
  const float* w_fc2 = (const float*)d_in[13];
  const float* b_fc2 = (const float*)d_in[14];
  float* out = (float*)d_out;
  const int mlp_blocks = (BDIM * LTOK) / GG;  // 2048

  if (ws_size >= (size_t)W_TOT * sizeof(unsigned short)) {
    unsigned short* ws = (unsigned short*)d_ws;
    prep_weights<<<(W_TOT + 255) / 256, 256, 0, stream>>>(w_qkv, w_proj, w_fc1, w_fc2, ws);
    attn_mlp_mfma<<<NWIN, 256, 0, stream>>>(x, b_qkv, w_lepe, b_lepe, b_proj,
                                            g1, bt1, g2, bt2, b_fc1, b_fc2, ws, out);
  } else {
    PF p{x, w_qkv, b_qkv, w_lepe, b_lepe, w_proj, b_proj,
         g1, bt1, g2, bt2, w_fc1, b_fc1, w_fc2, b_fc2, out};
    attn_scalar<<<NWIN, 256, 0, stream>>>(p);
    mlp_scalar<<<mlp_blocks, 256, 0, stream>>>(p);
  }
}